// Round 2
// baseline (259.875 us; speedup 1.0000x reference)
//
#include <hip/hip_runtime.h>

// 4 gaussians per thread: rot = 4x float4, scale = 3x float4, out = 9x float4,
// all naturally 16B-aligned per thread. No LDS, no barriers.

__device__ __forceinline__ void cov_one(const float4 q, const float s0, const float s1,
                                        const float s2, float* __restrict__ o)
{
    const float invn = rsqrtf(q.x * q.x + q.y * q.y + q.z * q.z + q.w * q.w);
    const float w = q.x * invn, x = q.y * invn, y = q.z * invn, z = q.w * invn;

    const float r00 = 1.f - 2.f * (y * y + z * z);
    const float r01 = 2.f * (x * y - w * z);
    const float r02 = 2.f * (x * z + w * y);
    const float r10 = 2.f * (x * y + w * z);
    const float r11 = 1.f - 2.f * (x * x + z * z);
    const float r12 = 2.f * (y * z - w * x);
    const float r20 = 2.f * (x * z - w * y);
    const float r21 = 2.f * (y * z + w * x);
    const float r22 = 1.f - 2.f * (x * x + y * y);

    const float m00 = r00 * s0, m01 = r01 * s1, m02 = r02 * s2;
    const float m10 = r10 * s0, m11 = r11 * s1, m12 = r12 * s2;
    const float m20 = r20 * s0, m21 = r21 * s1, m22 = r22 * s2;

    const float c00 = m00 * m00 + m01 * m01 + m02 * m02;
    const float c01 = m00 * m10 + m01 * m11 + m02 * m12;
    const float c02 = m00 * m20 + m01 * m21 + m02 * m22;
    const float c11 = m10 * m10 + m11 * m11 + m12 * m12;
    const float c12 = m10 * m20 + m11 * m21 + m12 * m22;
    const float c22 = m20 * m20 + m21 * m21 + m22 * m22;

    o[0] = c00; o[1] = c01; o[2] = c02;
    o[3] = c01; o[4] = c11; o[5] = c12;
    o[6] = c02; o[7] = c12; o[8] = c22;
}

__global__ __launch_bounds__(256) void cov4_kernel(
    const float4* __restrict__ rot4,
    const float4* __restrict__ scale4,
    float4* __restrict__ out4,
    int nq)   // nq = N/4 quad-groups
{
    const int i = blockIdx.x * 256 + threadIdx.x;
    if (i >= nq) return;

    const size_t ib = (size_t)i;
    const float4 q0 = rot4[ib * 4 + 0];
    const float4 q1 = rot4[ib * 4 + 1];
    const float4 q2 = rot4[ib * 4 + 2];
    const float4 q3 = rot4[ib * 4 + 3];
    const float4 sA = scale4[ib * 3 + 0];
    const float4 sB = scale4[ib * 3 + 1];
    const float4 sC = scale4[ib * 3 + 2];

    __align__(16) float o[36];
    cov_one(q0, sA.x, sA.y, sA.z, o + 0);
    cov_one(q1, sA.w, sB.x, sB.y, o + 9);
    cov_one(q2, sB.z, sB.w, sC.x, o + 18);
    cov_one(q3, sC.y, sC.z, sC.w, o + 27);

    const float4* ov = (const float4*)o;
    float4* ob = out4 + ib * 9;
#pragma unroll
    for (int k = 0; k < 9; ++k) ob[k] = ov[k];
}

// Tail for N % 4 != 0 (not expected for N = 4,000,000).
__global__ void cov_tail_kernel(
    const float* __restrict__ rot,
    const float* __restrict__ scale,
    float* __restrict__ out,
    int start, int n)
{
    int i = start + blockIdx.x * blockDim.x + threadIdx.x;
    if (i >= n) return;
    const float4 q = make_float4(rot[i * 4 + 0], rot[i * 4 + 1], rot[i * 4 + 2], rot[i * 4 + 3]);
    float o[9];
    cov_one(q, scale[i * 3 + 0], scale[i * 3 + 1], scale[i * 3 + 2], o);
    float* dst = out + (size_t)i * 9;
#pragma unroll
    for (int k = 0; k < 9; ++k) dst[k] = o[k];
}

extern "C" void kernel_launch(void* const* d_in, const int* in_sizes, int n_in,
                              void* d_out, int out_size, void* d_ws, size_t ws_size,
                              hipStream_t stream) {
    const float* rot   = (const float*)d_in[0];   // (N,4) fp32
    const float* scale = (const float*)d_in[1];   // (N,3) fp32
    float* out = (float*)d_out;                   // (N,3,3) fp32

    const int N  = in_sizes[0] / 4;
    const int nq = N / 4;                 // quad-groups handled by main kernel
    const int rem_start = nq * 4;
    const int rem = N - rem_start;

    if (nq > 0) {
        cov4_kernel<<<(nq + 255) / 256, 256, 0, stream>>>(
            (const float4*)rot, (const float4*)scale, (float4*)out, nq);
    }
    if (rem > 0) {
        cov_tail_kernel<<<(rem + 255) / 256, 256, 0, stream>>>(
            rot, scale, out, rem_start, N);
    }
}

// Round 3
// 227.754 us; speedup vs baseline: 1.1410x; 1.1410x over previous
//
#include <hip/hip_runtime.h>

// 1 gaussian/thread, 256 threads/block.
// Loads: rot as float4 (perfectly coalesced); scale as 3 scalar dwords
//   (lane-stride 12B -> same-line lane requests HW-coalesced, L1 absorbs repeats).
// Stores: stage 9 floats/thread into LDS (stride-9 = 2-way bank aliasing, free),
//   one barrier, then drain 576 float4/block with consecutive-lane 16B stores
//   (fully coalesced -- this is what round 2's 144B-lane-stride stores broke).

__device__ __forceinline__ void cov_compute(const float4 q, const float s0, const float s1,
                                            const float s2, float c[6])
{
    const float invn = rsqrtf(q.x * q.x + q.y * q.y + q.z * q.z + q.w * q.w);
    const float w = q.x * invn, x = q.y * invn, y = q.z * invn, z = q.w * invn;

    const float r00 = 1.f - 2.f * (y * y + z * z);
    const float r01 = 2.f * (x * y - w * z);
    const float r02 = 2.f * (x * z + w * y);
    const float r10 = 2.f * (x * y + w * z);
    const float r11 = 1.f - 2.f * (x * x + z * z);
    const float r12 = 2.f * (y * z - w * x);
    const float r20 = 2.f * (x * z - w * y);
    const float r21 = 2.f * (y * z + w * x);
    const float r22 = 1.f - 2.f * (x * x + y * y);

    const float m00 = r00 * s0, m01 = r01 * s1, m02 = r02 * s2;
    const float m10 = r10 * s0, m11 = r11 * s1, m12 = r12 * s2;
    const float m20 = r20 * s0, m21 = r21 * s1, m22 = r22 * s2;

    c[0] = m00 * m00 + m01 * m01 + m02 * m02;   // c00
    c[1] = m00 * m10 + m01 * m11 + m02 * m12;   // c01
    c[2] = m00 * m20 + m01 * m21 + m02 * m22;   // c02
    c[3] = m10 * m10 + m11 * m11 + m12 * m12;   // c11
    c[4] = m10 * m20 + m11 * m21 + m12 * m22;   // c12
    c[5] = m20 * m20 + m21 * m21 + m22 * m22;   // c22
}

__global__ __launch_bounds__(256) void cov_kernel(
    const float4* __restrict__ rot4,
    const float* __restrict__ scale,
    float4* __restrict__ out4)
{
    __shared__ __align__(16) float s_out[2304];   // 256 * 9
    const int t = threadIdx.x;
    const long long b = blockIdx.x;
    const long long i = b * 256 + t;

    const float4 q = rot4[i];
    const float s0 = scale[i * 3 + 0];
    const float s1 = scale[i * 3 + 1];
    const float s2 = scale[i * 3 + 2];

    float c[6];
    cov_compute(q, s0, s1, s2, c);

    float* so = &s_out[t * 9];
    so[0] = c[0]; so[1] = c[1]; so[2] = c[2];
    so[3] = c[1]; so[4] = c[3]; so[5] = c[4];
    so[6] = c[2]; so[7] = c[4]; so[8] = c[5];
    __syncthreads();

    const float4* sv = (const float4*)s_out;
    float4* ob = out4 + b * 576;
    ob[t]       = sv[t];
    ob[t + 256] = sv[t + 256];
    if (t < 64) ob[t + 512] = sv[t + 512];
}

// Tail for N % 256 != 0 (not expected for N = 4,000,000).
__global__ void cov_tail_kernel(
    const float* __restrict__ rot,
    const float* __restrict__ scale,
    float* __restrict__ out,
    int start, int n)
{
    int i = start + blockIdx.x * blockDim.x + threadIdx.x;
    if (i >= n) return;
    const float4 q = make_float4(rot[i * 4 + 0], rot[i * 4 + 1], rot[i * 4 + 2], rot[i * 4 + 3]);
    float c[6];
    cov_compute(q, scale[i * 3 + 0], scale[i * 3 + 1], scale[i * 3 + 2], c);
    float* o = out + (size_t)i * 9;
    o[0] = c[0]; o[1] = c[1]; o[2] = c[2];
    o[3] = c[1]; o[4] = c[3]; o[5] = c[4];
    o[6] = c[2]; o[7] = c[4]; o[8] = c[5];
}

extern "C" void kernel_launch(void* const* d_in, const int* in_sizes, int n_in,
                              void* d_out, int out_size, void* d_ws, size_t ws_size,
                              hipStream_t stream) {
    const float* rot   = (const float*)d_in[0];   // (N,4) fp32
    const float* scale = (const float*)d_in[1];   // (N,3) fp32
    float* out = (float*)d_out;                   // (N,3,3) fp32

    const int N = in_sizes[0] / 4;
    const int nfull = N / 256;
    const int rem_start = nfull * 256;
    const int rem = N - rem_start;

    if (nfull > 0) {
        cov_kernel<<<nfull, 256, 0, stream>>>(
            (const float4*)rot, scale, (float4*)out);
    }
    if (rem > 0) {
        cov_tail_kernel<<<(rem + 255) / 256, 256, 0, stream>>>(
            rot, scale, out, rem_start, N);
    }
}